// Round 16
// baseline (483.682 us; speedup 1.0000x reference)
//
#include <hip/hip_runtime.h>
#include <hip/hip_bf16.h>

#define E 1024
#define F 12
#define BM 16        // rows per tile
#define KHALF 512    // K per block (2 blocks per tile)

typedef float f32x4_t __attribute__((ext_vector_type(4)));
typedef short bf16x8  __attribute__((ext_vector_type(8)));

__device__ __forceinline__ short f2bf(float f) {
    return (short)__builtin_bit_cast(unsigned short, __float2bfloat16(f));
}

// ---------------- split-K pair kernel ----------------------------------------
// Block bid: tile = bid>>1, half = bid&1 reads x[tile rows][half*512 .. +512).
// Both halves write 16x12 h-partials to ws; last-arriving block (atomic) sums,
// applies relu/theta/cos, and streams the 64KB output tile.
__global__ __launch_bounds__(256, 4) void ffq_split(
    const float* __restrict__ x,
    const float* __restrict__ W1,
    const float* __restrict__ b1,
    const float* __restrict__ theta,
    const float* __restrict__ W2,
    const float* __restrict__ b2,
    float* __restrict__ out,
    int* __restrict__ cnt,          // ws: one counter per tile (zeroed per launch)
    float* __restrict__ partials,   // ws: [tile][half][192] floats
    int nrows)
{
    const int tid  = threadIdx.x;
    const int lane = tid & 63;
    const int wave = tid >> 6;     // wave w covers k in [half*512 + w*128, +128)
    const int g    = lane >> 4;
    const int n    = lane & 15;    // A row (m) on loads / C col (f)

    const int tile = blockIdx.x >> 1;
    const int half = blockIdx.x & 1;
    const int row0 = tile * BM;
    if (row0 >= nrows) return;

    __shared__ __align__(16) float red[4][64][4];
    __shared__ __align__(16) float qsh[16][20];
    __shared__ int flag;

    // ---- phase 1: partial h over this block's K-half via MFMA ----
    const int nc = (n < F) ? n : (F - 1);
    const int mrow = min(row0 + n, nrows - 1);
    const int k0 = half * KHALF + wave * 128 + g * 8;
    const float* xrow = x  + (size_t)mrow * E + k0;
    const float* wrow = W1 + (size_t)nc   * E + k0;

    f32x4_t acc0 = {0.f,0.f,0.f,0.f}, acc1 = {0.f,0.f,0.f,0.f};
#pragma unroll
    for (int ks = 0; ks < 4; ++ks) {
        f32x4_t a0 = *reinterpret_cast<const f32x4_t*>(xrow + ks * 32);
        f32x4_t a1 = *reinterpret_cast<const f32x4_t*>(xrow + ks * 32 + 4);
        f32x4_t b0 = *reinterpret_cast<const f32x4_t*>(wrow + ks * 32);
        f32x4_t b1v= *reinterpret_cast<const f32x4_t*>(wrow + ks * 32 + 4);
        bf16x8 af, bfr;
#pragma unroll
        for (int j = 0; j < 4; ++j) {
            af[j]      = f2bf(a0[j]);
            af[j + 4]  = f2bf(a1[j]);
            bfr[j]     = f2bf(b0[j]);
            bfr[j + 4] = f2bf(b1v[j]);
        }
        if (ks & 1) acc1 = __builtin_amdgcn_mfma_f32_16x16x32_bf16(af, bfr, acc1, 0, 0, 0);
        else        acc0 = __builtin_amdgcn_mfma_f32_16x16x32_bf16(af, bfr, acc0, 0, 0, 0);
    }
    *reinterpret_cast<f32x4_t*>(&red[wave][lane][0]) = acc0 + acc1;

    __syncthreads();

    // ---- wave 0: combine 4 wave-partials, write 16x12 slab to ws ----
    float* slab = partials + ((size_t)tile * 2 + half) * 192;
    if (wave == 0) {
        f32x4_t r0 = *reinterpret_cast<const f32x4_t*>(&red[0][lane][0]);
        f32x4_t r1 = *reinterpret_cast<const f32x4_t*>(&red[1][lane][0]);
        f32x4_t r2 = *reinterpret_cast<const f32x4_t*>(&red[2][lane][0]);
        f32x4_t r3 = *reinterpret_cast<const f32x4_t*>(&red[3][lane][0]);
        f32x4_t s  = (r0 + r1) + (r2 + r3);
        if (n < F) {
#pragma unroll
            for (int j = 0; j < 4; ++j)
                slab[(g * 4 + j) * F + n] = s[j];   // C row m = g*4+j
        }
    }

    __threadfence();                       // release: slab visible device-wide
    if (tid == 0) flag = atomicAdd(&cnt[tile], 1);
    __syncthreads();
    if (flag == 0) return;                 // first arriver: pure reader, retire
    __threadfence();                       // acquire: see buddy's slab

    // ---- winner: q = cos(relu(s0+s1+b1)+theta), fixed order -> deterministic ----
    const float* s0 = partials + ((size_t)tile * 2 + 0) * 192;
    const float* s1 = partials + ((size_t)tile * 2 + 1) * 192;
    if (tid < 16 * F) {
        const int m = tid / F, f = tid - m * F;
        const float s = s0[tid] + s1[tid] + b1[f];
        qsh[m][f] = __cosf(fmaxf(s, 0.0f) + theta[f]);
    }

    float w2l[48];                 // W2[(4t+j)][f] = w2l[12j+f]
#pragma unroll
    for (int k2 = 0; k2 < 12; ++k2)
        *reinterpret_cast<f32x4_t*>(&w2l[4 * k2]) =
            *reinterpret_cast<const f32x4_t*>(W2 + (size_t)tid * 48 + 4 * k2);
    const f32x4_t bias2 = *reinterpret_cast<const f32x4_t*>(b2 + tid * 4);

    __syncthreads();

    // ---- phase 2: out = q.W2^T + b2, nontemporal f32x4 stores ----
    float* orow = out + (size_t)row0 * E + tid * 4;
#pragma unroll 4
    for (int m = 0; m < BM; ++m) {
        if (row0 + m < nrows) {
            float qf[F];
            *reinterpret_cast<f32x4_t*>(&qf[0]) = *reinterpret_cast<const f32x4_t*>(&qsh[m][0]);
            *reinterpret_cast<f32x4_t*>(&qf[4]) = *reinterpret_cast<const f32x4_t*>(&qsh[m][4]);
            *reinterpret_cast<f32x4_t*>(&qf[8]) = *reinterpret_cast<const f32x4_t*>(&qsh[m][8]);
            f32x4_t o;
#pragma unroll
            for (int j = 0; j < 4; ++j) {
                float a = bias2[j];
#pragma unroll
                for (int f = 0; f < F; ++f) a = fmaf(qf[f], w2l[12 * j + f], a);
                o[j] = a;
            }
            __builtin_nontemporal_store(o, reinterpret_cast<f32x4_t*>(orow + (size_t)m * E));
        }
    }
}

// ---------------- fallback: proven R7 fused kernel (29.5 us) -----------------
__global__ __launch_bounds__(256, 4) void ffq_mfma(
    const float* __restrict__ x, const float* __restrict__ W1,
    const float* __restrict__ b1, const float* __restrict__ theta,
    const float* __restrict__ W2, const float* __restrict__ b2,
    float* __restrict__ out, int nrows)
{
    const int tid  = threadIdx.x;
    const int lane = tid & 63;
    const int wave = tid >> 6;
    const int g    = lane >> 4;
    const int n    = lane & 15;

    const int row0 = blockIdx.x * BM;
    if (row0 >= nrows) return;

    __shared__ __align__(16) float red[4][64][4];
    __shared__ __align__(16) float qsh[16][20];

    const int nc = (n < F) ? n : (F - 1);
    const float b1n = b1[nc], thn = theta[nc];

    const int mrow = min(row0 + n, nrows - 1);
    const float* xrow = x  + (size_t)mrow * E + wave * 256 + g * 8;
    const float* wrow = W1 + (size_t)nc   * E + wave * 256 + g * 8;

    f32x4_t acc0 = {0.f,0.f,0.f,0.f}, acc1 = {0.f,0.f,0.f,0.f};
#pragma unroll
    for (int ks = 0; ks < 8; ++ks) {
        f32x4_t a0 = *reinterpret_cast<const f32x4_t*>(xrow + ks * 32);
        f32x4_t a1 = *reinterpret_cast<const f32x4_t*>(xrow + ks * 32 + 4);
        f32x4_t b0 = *reinterpret_cast<const f32x4_t*>(wrow + ks * 32);
        f32x4_t b1v= *reinterpret_cast<const f32x4_t*>(wrow + ks * 32 + 4);
        bf16x8 af, bfr;
#pragma unroll
        for (int j = 0; j < 4; ++j) {
            af[j] = f2bf(a0[j]); af[j + 4] = f2bf(a1[j]);
            bfr[j] = f2bf(b0[j]); bfr[j + 4] = f2bf(b1v[j]);
        }
        if (ks & 1) acc1 = __builtin_amdgcn_mfma_f32_16x16x32_bf16(af, bfr, acc1, 0, 0, 0);
        else        acc0 = __builtin_amdgcn_mfma_f32_16x16x32_bf16(af, bfr, acc0, 0, 0, 0);
    }
    *reinterpret_cast<f32x4_t*>(&red[wave][lane][0]) = acc0 + acc1;

    __syncthreads();

    float w2l[48];
#pragma unroll
    for (int k2 = 0; k2 < 12; ++k2)
        *reinterpret_cast<f32x4_t*>(&w2l[4 * k2]) =
            *reinterpret_cast<const f32x4_t*>(W2 + (size_t)tid * 48 + 4 * k2);
    const f32x4_t bias2 = *reinterpret_cast<const f32x4_t*>(b2 + tid * 4);

    {
        f32x4_t r0 = *reinterpret_cast<const f32x4_t*>(&red[0][lane][0]);
        f32x4_t r1 = *reinterpret_cast<const f32x4_t*>(&red[1][lane][0]);
        f32x4_t r2 = *reinterpret_cast<const f32x4_t*>(&red[2][lane][0]);
        f32x4_t r3 = *reinterpret_cast<const f32x4_t*>(&red[3][lane][0]);
        f32x4_t s  = (r0 + r1) + (r2 + r3);
#pragma unroll
        for (int j = 0; j < 4; ++j)
            qsh[g * 4 + j][n] = __cosf(fmaxf(s[j] + b1n, 0.0f) + thn);
    }

    float* orow = out + (size_t)row0 * E + tid * 4;
#pragma unroll 4
    for (int m = 0; m < BM; ++m) {
        if (row0 + m < nrows) {
            float qf[F];
            *reinterpret_cast<f32x4_t*>(&qf[0]) = *reinterpret_cast<const f32x4_t*>(&qsh[m][0]);
            *reinterpret_cast<f32x4_t*>(&qf[4]) = *reinterpret_cast<const f32x4_t*>(&qsh[m][4]);
            *reinterpret_cast<f32x4_t*>(&qf[8]) = *reinterpret_cast<const f32x4_t*>(&qsh[m][8]);
            f32x4_t o;
#pragma unroll
            for (int j = 0; j < 4; ++j) {
                float a = bias2[j];
#pragma unroll
                for (int f = 0; f < F; ++f) a = fmaf(qf[f], w2l[12 * j + f], a);
                o[j] = a;
            }
            __builtin_nontemporal_store(o, reinterpret_cast<f32x4_t*>(orow + (size_t)m * E));
        }
    }
}

extern "C" void kernel_launch(void* const* d_in, const int* in_sizes, int n_in,
                              void* d_out, int out_size, void* d_ws, size_t ws_size,
                              hipStream_t stream)
{
    const float* x     = (const float*)d_in[0];
    const float* W1    = (const float*)d_in[1];
    const float* b1    = (const float*)d_in[2];
    const float* theta = (const float*)d_in[3];
    const float* W2    = (const float*)d_in[4];
    const float* b2    = (const float*)d_in[5];
    float* out = (float*)d_out;

    const int nrows = in_sizes[0] / E;             // B*S = 16384
    const int tiles = (nrows + BM - 1) / BM;       // 1024

    const size_t cnt_bytes  = (size_t)tiles * sizeof(int);
    const size_t part_off   = 4096;                // keep partials 4KB-aligned
    const size_t need_ws    = part_off + (size_t)tiles * 2 * 192 * sizeof(float);

    if (ws_size >= need_ws) {
        int*   cnt      = (int*)d_ws;
        float* partials = (float*)((char*)d_ws + part_off);
        hipMemsetAsync(cnt, 0, cnt_bytes, stream);               // capture-legal
        ffq_split<<<tiles * 2, 256, 0, stream>>>(x, W1, b1, theta, W2, b2, out,
                                                 cnt, partials, nrows);
    } else {
        ffq_mfma<<<tiles, 256, 0, stream>>>(x, W1, b1, theta, W2, b2, out, nrows);
    }
}

// Round 18
// 29.892 us; speedup vs baseline: 16.1810x; 16.1810x over previous
//
#include <hip/hip_runtime.h>
#include <hip/hip_bf16.h>

#define E 1024
#define F 12
#define BM 16   // rows per block

typedef float f32x4_t __attribute__((ext_vector_type(4)));
typedef short bf16x8  __attribute__((ext_vector_type(8)));

// float -> bf16 bits (RNE)
__device__ __forceinline__ short f2bf(float f) {
    return (short)__builtin_bit_cast(unsigned short, __float2bfloat16(f));
}

// order-pinned 16B load the scheduler cannot sink: asm volatile + "memory".
// OFF is a literal byte offset (13-bit signed range).
#define GL16(dst, base, OFF)                                        \
    asm volatile("global_load_dwordx4 %0, %1, off offset:" OFF      \
                 : "=&v"(dst) : "v"(base) : "memory")

// launch_bounds(256,2): VGPR cap 256 so the 32 asm-defined f32x4 results plus
// compiler temps (~170 live) NEVER spill — regalloc movement between an asm
// load and its s_waitcnt reads unready registers (R16's correctness failure).
__global__ __launch_bounds__(256, 2) void ffq_mfma(
    const float* __restrict__ x,
    const float* __restrict__ W1,
    const float* __restrict__ b1,
    const float* __restrict__ theta,
    const float* __restrict__ W2,
    const float* __restrict__ b2,
    float* __restrict__ out, int nrows)
{
    const int tid  = threadIdx.x;
    const int lane = tid & 63;
    const int wave = tid >> 6;     // K-split: wave w covers k in [w*256, (w+1)*256)
    const int g    = lane >> 4;    // k sub-group within the fragment
    const int n    = lane & 15;    // MFMA: A row (m) / B col (f) / C col

    const int row0 = blockIdx.x * BM;
    if (row0 >= nrows) return;

    __shared__ __align__(16) float red[4][64][4];  // per-wave partial C
    __shared__ __align__(16) float qsh[16][20];    // q[m][f], padded row

    const int nc = (n < F) ? n : (F - 1);          // clamp: C cols 12..15 unused
    const float b1n = b1[nc], thn = theta[nc];

    // ---------------- phase 1: h = x . W1^T via MFMA ----------------
    // A slot (g,j) <- x[row0+n][kb + g*8 + j]; B slot (g,j) <- W1[nc][same k].
    // Same (g,j)->k map for A and B => contraction correct for any bijection.
    const int mrow = min(row0 + n, nrows - 1);
    const float* xrow = x  + (size_t)mrow * E + wave * 256 + g * 8;
    const float* wrow = W1 + (size_t)nc   * E + wave * 256 + g * 8;

    // ---- deep MLP batch: 32 order-pinned loads, ONE vmcnt drain ----
    // 16 x-loads (256 B/lane) + 16 W1-loads in flight simultaneously.
    f32x4_t xa[16];
    GL16(xa[0],  xrow, "0");   GL16(xa[1],  xrow, "16");
    GL16(xa[2],  xrow, "128"); GL16(xa[3],  xrow, "144");
    GL16(xa[4],  xrow, "256"); GL16(xa[5],  xrow, "272");
    GL16(xa[6],  xrow, "384"); GL16(xa[7],  xrow, "400");
    GL16(xa[8],  xrow, "512"); GL16(xa[9],  xrow, "528");
    GL16(xa[10], xrow, "640"); GL16(xa[11], xrow, "656");
    GL16(xa[12], xrow, "768"); GL16(xa[13], xrow, "784");
    GL16(xa[14], xrow, "896"); GL16(xa[15], xrow, "912");

    f32x4_t wa[16];
    GL16(wa[0],  wrow, "0");   GL16(wa[1],  wrow, "16");
    GL16(wa[2],  wrow, "128"); GL16(wa[3],  wrow, "144");
    GL16(wa[4],  wrow, "256"); GL16(wa[5],  wrow, "272");
    GL16(wa[6],  wrow, "384"); GL16(wa[7],  wrow, "400");
    GL16(wa[8],  wrow, "512"); GL16(wa[9],  wrow, "528");
    GL16(wa[10], wrow, "640"); GL16(wa[11], wrow, "656");
    GL16(wa[12], wrow, "768"); GL16(wa[13], wrow, "784");
    GL16(wa[14], wrow, "896"); GL16(wa[15], wrow, "912");

    asm volatile("s_waitcnt vmcnt(0)" ::: "memory");
    __builtin_amdgcn_sched_barrier(0);   // rule #18: no consumer hoists above wait

    f32x4_t acc0 = {0.f, 0.f, 0.f, 0.f}, acc1 = {0.f, 0.f, 0.f, 0.f};
#pragma unroll
    for (int ks = 0; ks < 8; ++ks) {
        bf16x8 af, bfr;
#pragma unroll
        for (int j = 0; j < 4; ++j) {
            af[j]      = f2bf(xa[2 * ks][j]);
            af[j + 4]  = f2bf(xa[2 * ks + 1][j]);
            bfr[j]     = f2bf(wa[2 * ks][j]);
            bfr[j + 4] = f2bf(wa[2 * ks + 1][j]);
        }
        if (ks & 1) acc1 = __builtin_amdgcn_mfma_f32_16x16x32_bf16(af, bfr, acc1, 0, 0, 0);
        else        acc0 = __builtin_amdgcn_mfma_f32_16x16x32_bf16(af, bfr, acc0, 0, 0, 0);
    }
    *reinterpret_cast<f32x4_t*>(&red[wave][lane][0]) = acc0 + acc1;

    __syncthreads();   // the only block barrier

    // ---- epilogue operands (L2-resident) ----
    float w2l[48];                 // W2[(4t+j)][f] = w2l[12j+f]
#pragma unroll
    for (int k2 = 0; k2 < 12; ++k2)
        *reinterpret_cast<f32x4_t*>(&w2l[4 * k2]) =
            *reinterpret_cast<const f32x4_t*>(W2 + (size_t)tid * 48 + 4 * k2);
    const f32x4_t bias2 = *reinterpret_cast<const f32x4_t*>(b2 + tid * 4);

    // ---- finisher: every wave computes the full 16x16 q tile identically
    //      (same LDS inputs, same order -> bitwise-identical; benign race) ----
    {
        f32x4_t r0 = *reinterpret_cast<const f32x4_t*>(&red[0][lane][0]);
        f32x4_t r1 = *reinterpret_cast<const f32x4_t*>(&red[1][lane][0]);
        f32x4_t r2 = *reinterpret_cast<const f32x4_t*>(&red[2][lane][0]);
        f32x4_t r3 = *reinterpret_cast<const f32x4_t*>(&red[3][lane][0]);
        f32x4_t s  = (r0 + r1) + (r2 + r3);
#pragma unroll
        for (int j = 0; j < 4; ++j) {
            const int m = g * 4 + j;            // C row (HW-verified C/D layout)
            qsh[m][n] = __cosf(fmaxf(s[j] + b1n, 0.0f) + thn);
        }
    }
    // phase2 reads qsh written by this same wave (program order) -> no 2nd barrier

    // ---------------- phase 2: out = q . W2^T + b2 (nontemporal stores) ------
    float* orow = out + (size_t)row0 * E + tid * 4;
#pragma unroll 4
    for (int m = 0; m < BM; ++m) {
        if (row0 + m < nrows) {
            float qf[F];
            *reinterpret_cast<f32x4_t*>(&qf[0]) = *reinterpret_cast<const f32x4_t*>(&qsh[m][0]);
            *reinterpret_cast<f32x4_t*>(&qf[4]) = *reinterpret_cast<const f32x4_t*>(&qsh[m][4]);
            *reinterpret_cast<f32x4_t*>(&qf[8]) = *reinterpret_cast<const f32x4_t*>(&qsh[m][8]);

            f32x4_t o;
#pragma unroll
            for (int j = 0; j < 4; ++j) {
                float a = bias2[j];
#pragma unroll
                for (int f = 0; f < F; ++f) a = fmaf(qf[f], w2l[12 * j + f], a);
                o[j] = a;
            }
            __builtin_nontemporal_store(o, reinterpret_cast<f32x4_t*>(orow + (size_t)m * E));
        }
    }
}

extern "C" void kernel_launch(void* const* d_in, const int* in_sizes, int n_in,
                              void* d_out, int out_size, void* d_ws, size_t ws_size,
                              hipStream_t stream)
{
    const float* x     = (const float*)d_in[0];
    const float* W1    = (const float*)d_in[1];
    const float* b1    = (const float*)d_in[2];
    const float* theta = (const float*)d_in[3];
    const float* W2    = (const float*)d_in[4];
    const float* b2    = (const float*)d_in[5];
    float* out = (float*)d_out;

    const int nrows = in_sizes[0] / E;             // B*S = 16384
    const int grid  = (nrows + BM - 1) / BM;       // 1024 blocks

    ffq_mfma<<<grid, 256, 0, stream>>>(x, W1, b1, theta, W2, b2, out, nrows);
}